// Round 1
// baseline (189.900 us; speedup 1.0000x reference)
//
#include <hip/hip_runtime.h>
#include <hip/hip_bf16.h>
#include <stdint.h>
#include <math.h>

typedef __bf16 bf16x8 __attribute__((ext_vector_type(8)));
typedef float f32x4 __attribute__((ext_vector_type(4)));

#define B_    2
#define S_    2048
#define D_    1024
#define H_    16
#define HKV_  4
#define HD_   64
#define MTOT  4096      // B*S
#define NQKV  1536      // H*HD + 2*HKV*HD

__device__ __forceinline__ unsigned short f2bf(float f) {
  union { float f; unsigned u; } v; v.f = f;
  unsigned r = (v.u + 0x7FFFu + ((v.u >> 16) & 1u)) >> 16;
  return (unsigned short)r;
}

__device__ __forceinline__ void gl_lds16(const void* g, void* l) {
  __builtin_amdgcn_global_load_lds((const __attribute__((address_space(1))) void*)g,
                                   (__attribute__((address_space(3))) void*)l, 16, 0, 0);
}

// ---------------- fp32 -> bf16 elementwise ----------------
__global__ __launch_bounds__(256) void k_f32_to_bf16(const float* __restrict__ in,
                                                     unsigned short* __restrict__ out, int n4) {
  int i = blockIdx.x * blockDim.x + threadIdx.x;
  int stride = gridDim.x * blockDim.x;
  for (; i < n4; i += stride) {
    float4 v = ((const float4*)in)[i];
    ushort4 o;
    o.x = f2bf(v.x); o.y = f2bf(v.y); o.z = f2bf(v.z); o.w = f2bf(v.w);
    ((ushort4*)out)[i] = o;
  }
}

// ---------------- RoPE cos/sin tables [S][32] ----------------
__global__ __launch_bounds__(256) void k_rope_tables(float* __restrict__ cost, float* __restrict__ sint) {
  int idx = blockIdx.x * blockDim.x + threadIdx.x;   // 0..65535
  int s = idx >> 5, i = idx & 31;
  double inv = exp(-(double)i / 32.0 * log(10000.0));
  double ang = (double)s * inv;
  cost[idx] = (float)cos(ang);
  sint[idx] = (float)sin(ang);
}

// ---------------- transpose fp32 [R][C] -> bf16 [C][R] (64x64 tiles) ----------------
__global__ __launch_bounds__(256) void k_transpose_w(const float* __restrict__ src, int ldsrc,
                                                     unsigned short* __restrict__ dst, int lddst) {
  int cb = blockIdx.x * 64, rb = blockIdx.y * 64;
  __shared__ unsigned short T[64][72];
  int tid = threadIdx.x;
  for (int rep = 0; rep < 4; ++rep) {
    int idx = rep * 256 + tid;          // 0..1023
    int r = idx >> 4, seg = idx & 15;
    float4 v = *(const float4*)&src[(size_t)(rb + r) * ldsrc + cb + seg * 4];
    T[seg*4+0][r] = f2bf(v.x);
    T[seg*4+1][r] = f2bf(v.y);
    T[seg*4+2][r] = f2bf(v.z);
    T[seg*4+3][r] = f2bf(v.w);
  }
  __syncthreads();
  for (int rep = 0; rep < 2; ++rep) {
    int idx = rep * 256 + tid;          // 0..511
    int c = idx >> 3, seg = idx & 7;
    *(uint4*)&dst[(size_t)(cb + c) * lddst + rb + seg * 8] = *(const uint4*)&T[c][seg * 8];
  }
}

// ---------------- bf16 GEMM: C[M][N] = A[M][K] * Bt[N][K]^T  (m97-style 128x128) ----------------
__global__ __launch_bounds__(256) void k_gemm_bt(const unsigned short* __restrict__ A,
                                                 const unsigned short* __restrict__ Bt,
                                                 float* __restrict__ C, int M, int N, int K) {
  int nb = blockIdx.x, mb = blockIdx.y;
  __shared__ unsigned short As[128 * 32];
  __shared__ unsigned short Bs[128 * 32];
  int tid = threadIdx.x, lane = tid & 63, w = tid >> 6;
  int wr = w >> 1, wc = w & 1;
  f32x4 acc[4][4];
  for (int m = 0; m < 4; ++m) for (int n = 0; n < 4; ++n) acc[m][n] = (f32x4){0.f, 0.f, 0.f, 0.f};

  const int r16 = lane >> 2;          // row within 16-row segment
  const int c8  = (lane & 3) * 8;     // col (elements)

  auto stage = [&](int kt) {
    for (int j = 0; j < 2; ++j) {
      int rbase = (w * 2 + j) * 16;
      gl_lds16(&A [(size_t)(mb * 128 + rbase + r16) * K + kt * 32 + c8], &As[rbase * 32]);
      gl_lds16(&Bt[(size_t)(nb * 128 + rbase + r16) * K + kt * 32 + c8], &Bs[rbase * 32]);
    }
  };
  stage(0);
  int NT = K / 32;
  for (int kt = 0; kt < NT; ++kt) {
    __syncthreads();                  // staging complete (compiler drains vmcnt)
    bf16x8 af[4], bfr[4];
    int lr = lane & 15, lg8 = (lane >> 4) * 8;
    for (int m = 0; m < 4; ++m) af[m]  = *(const bf16x8*)&As[(wr * 64 + m * 16 + lr) * 32 + lg8];
    for (int n = 0; n < 4; ++n) bfr[n] = *(const bf16x8*)&Bs[(wc * 64 + n * 16 + lr) * 32 + lg8];
    for (int m = 0; m < 4; ++m)
      for (int n = 0; n < 4; ++n)
        acc[m][n] = __builtin_amdgcn_mfma_f32_16x16x32_bf16(af[m], bfr[n], acc[m][n], 0, 0, 0);
    __syncthreads();                  // all frag reads done before restage
    if (kt + 1 < NT) stage(kt + 1);
  }
  int lr = lane & 15, lq = (lane >> 4) * 4;
  for (int m = 0; m < 4; ++m)
    for (int n = 0; n < 4; ++n)
      for (int r = 0; r < 4; ++r)
        C[(size_t)(mb * 128 + wr * 64 + m * 16 + lq + r) * N + nb * 128 + wc * 64 + n * 16 + lr] = acc[m][n][r];
}

// ---------------- RoPE apply + layout: qkv fp32 -> Qb[B,H,S,64], Kb[B,HKV,S,64] bf16 ----------------
__global__ __launch_bounds__(256) void k_rope_qk(const float* __restrict__ qkv,
                                                 const float* __restrict__ cost,
                                                 const float* __restrict__ sint,
                                                 unsigned short* __restrict__ Qb,
                                                 unsigned short* __restrict__ Kb) {
  int blk = blockIdx.x;               // b*S + s
  int b = blk >> 11, s = blk & 2047;
  int tid = threadIdx.x;
  const float* row = qkv + (size_t)blk * NQKV;
  for (int rep = 0; rep < 4; ++rep) {
    int e = rep * 256 + tid;          // 0..1023
    int h = e >> 6, d = e & 63, d2 = d & 31;
    float c = cost[s * 32 + d2], sn = sint[s * 32 + d2];
    float x = row[e], xp = row[e ^ 32];
    float rot = (d < 32) ? -xp : xp;
    float o = (x * c + rot * sn) * 0.125f;   // fold 1/sqrt(64): exact in bf16
    Qb[(((size_t)(b * H_ + h)) * S_ + s) * HD_ + d] = f2bf(o);
  }
  {
    int e = tid;                      // 0..255
    int hk = e >> 6, d = e & 63, d2 = d & 31;
    float c = cost[s * 32 + d2], sn = sint[s * 32 + d2];
    float x = row[1024 + e], xp = row[1024 + (e ^ 32)];
    float rot = (d < 32) ? -xp : xp;
    float o = x * c + rot * sn;
    Kb[(((size_t)(b * HKV_ + hk)) * S_ + s) * HD_ + d] = f2bf(o);
  }
}

// ---------------- V transpose: qkv fp32 v-part -> Vt[B,HKV,64,S] bf16 ----------------
__global__ __launch_bounds__(256) void k_v_transpose(const float* __restrict__ qkv,
                                                     unsigned short* __restrict__ Vt) {
  int sb = blockIdx.x * 64;
  int b = blockIdx.y >> 2, hk = blockIdx.y & 3;
  __shared__ unsigned short T[64][72];
  int tid = threadIdx.x;
  for (int rep = 0; rep < 4; ++rep) {
    int idx = rep * 256 + tid;        // 0..1023
    int i = idx >> 4, seg = idx & 15;
    float4 v = *(const float4*)&qkv[((size_t)(b * S_ + sb + i)) * NQKV + 1280 + hk * 64 + seg * 4];
    T[seg*4+0][i] = f2bf(v.x);
    T[seg*4+1][i] = f2bf(v.y);
    T[seg*4+2][i] = f2bf(v.z);
    T[seg*4+3][i] = f2bf(v.w);
  }
  __syncthreads();
  for (int rep = 0; rep < 2; ++rep) {
    int idx = rep * 256 + tid;        // 0..511
    int d = idx >> 3, seg = idx & 7;
    *(uint4*)&Vt[(((size_t)(b * HKV_ + hk)) * HD_ + d) * S_ + sb + seg * 8] = *(const uint4*)&T[d][seg * 8];
  }
}

// ---------------- flash attention: 4 waves x 16 q-rows, KBLK=64, swapped QK^T ----------------
__global__ __launch_bounds__(256) void k_attn(const unsigned short* __restrict__ Q,
                                              const unsigned short* __restrict__ K,
                                              const unsigned short* __restrict__ Vt,
                                              unsigned short* __restrict__ O) {
  int qt = blockIdx.x;                // 0..31 (q tile of 64)
  int bh = blockIdx.y;                // 0..31
  int b = bh >> 4, h = bh & 15, hk = h >> 2;
  const unsigned short* Qp = Q + (((size_t)(b * H_ + h)) * S_ + qt * 64) * HD_;
  const unsigned short* Kp = K + ((size_t)(b * HKV_ + hk)) * S_ * HD_;
  const unsigned short* Vp = Vt + ((size_t)(b * HKV_ + hk)) * HD_ * S_;

  __shared__ unsigned short Qs[64][72];
  __shared__ unsigned short Ks[64][72];
  __shared__ unsigned short Vs[64][72];     // V^T tile: [d][k]
  __shared__ unsigned short Ps[4][16][72];  // per-wave P: [q][k]

  int tid = threadIdx.x, lane = tid & 63, w = tid >> 6;
  const int lr = lane & 15, lg = lane >> 4;

  for (int rep = 0; rep < 2; ++rep) {
    int idx = rep * 256 + tid;        // 0..511
    int r = idx >> 3, c = (idx & 7) * 8;
    *(uint4*)&Qs[r][c] = *(const uint4*)&Qp[r * 64 + c];
  }
  __syncthreads();
  bf16x8 qf0 = *(const bf16x8*)&Qs[w * 16 + lr][lg * 8];
  bf16x8 qf1 = *(const bf16x8*)&Qs[w * 16 + lr][32 + lg * 8];

  f32x4 oacc[4];
  for (int dg = 0; dg < 4; ++dg) oacc[dg] = (f32x4){0.f, 0.f, 0.f, 0.f};
  float m_run = -1e30f, l_run = 0.f;

  for (int kt = 0; kt < S_ / 64; ++kt) {
    __syncthreads();                  // prev tile fully consumed
    for (int rep = 0; rep < 2; ++rep) {
      int idx = rep * 256 + tid;      // 0..511
      int r = idx >> 3, c = (idx & 7) * 8;
      *(uint4*)&Ks[r][c] = *(const uint4*)&Kp[(size_t)(kt * 64 + r) * 64 + c];
      *(uint4*)&Vs[r][c] = *(const uint4*)&Vp[(size_t)r * S_ + kt * 64 + c];
    }
    __syncthreads();

    // S^T[key][q] = K * Q^T   (keys = kg*16 + lg*4 + r for this lane's column q=lr)
    f32x4 st[4];
    for (int kg = 0; kg < 4; ++kg) {
      bf16x8 kf0 = *(const bf16x8*)&Ks[kg * 16 + lr][lg * 8];
      bf16x8 kf1 = *(const bf16x8*)&Ks[kg * 16 + lr][32 + lg * 8];
      f32x4 z = (f32x4){0.f, 0.f, 0.f, 0.f};
      z = __builtin_amdgcn_mfma_f32_16x16x32_bf16(kf0, qf0, z, 0, 0, 0);
      z = __builtin_amdgcn_mfma_f32_16x16x32_bf16(kf1, qf1, z, 0, 0, 0);
      st[kg] = z;
    }

    // online softmax per q-column (lanes {lr, lr+16, lr+32, lr+48} share q)
    float tmax = -1e30f;
    for (int kg = 0; kg < 4; ++kg)
      for (int r = 0; r < 4; ++r) tmax = fmaxf(tmax, st[kg][r]);
    tmax = fmaxf(tmax, __shfl_xor(tmax, 16));
    tmax = fmaxf(tmax, __shfl_xor(tmax, 32));
    float m_new = fmaxf(m_run, tmax);
    float fac = exp2f((m_run - m_new) * 1.44269504f);
    float psum = 0.f;
    unsigned short pb[4][4];
    for (int kg = 0; kg < 4; ++kg)
      for (int r = 0; r < 4; ++r) {
        float p = exp2f((st[kg][r] - m_new) * 1.44269504f);
        psum += p;
        pb[kg][r] = f2bf(p);
      }
    psum += __shfl_xor(psum, 16);
    psum += __shfl_xor(psum, 32);
    l_run = l_run * fac + psum;
    m_run = m_new;

    for (int kg = 0; kg < 4; ++kg)
      for (int r = 0; r < 4; ++r)
        Ps[w][lr][kg * 16 + lg * 4 + r] = pb[kg][r];
    asm volatile("" ::: "memory");    // keep LDS write->read order (in-order LDS pipe)

    bf16x8 pf0 = *(const bf16x8*)&Ps[w][lr][lg * 8];
    bf16x8 pf1 = *(const bf16x8*)&Ps[w][lr][32 + lg * 8];

    float facs[4];
    for (int r = 0; r < 4; ++r) facs[r] = __shfl(fac, lg * 4 + r, 64);
    for (int dg = 0; dg < 4; ++dg) {
      for (int r = 0; r < 4; ++r) oacc[dg][r] *= facs[r];
      bf16x8 vf0 = *(const bf16x8*)&Vs[dg * 16 + lr][lg * 8];
      bf16x8 vf1 = *(const bf16x8*)&Vs[dg * 16 + lr][32 + lg * 8];
      oacc[dg] = __builtin_amdgcn_mfma_f32_16x16x32_bf16(pf0, vf0, oacc[dg], 0, 0, 0);
      oacc[dg] = __builtin_amdgcn_mfma_f32_16x16x32_bf16(pf1, vf1, oacc[dg], 0, 0, 0);
    }
  }

  float linv[4];
  for (int r = 0; r < 4; ++r) linv[r] = 1.f / __shfl(l_run, lg * 4 + r, 64);
  for (int dg = 0; dg < 4; ++dg)
    for (int r = 0; r < 4; ++r) {
      int srow = qt * 64 + w * 16 + lg * 4 + r;
      int col = h * 64 + dg * 16 + lr;
      O[((size_t)(b * S_) + srow) * D_ + col] = f2bf(oacc[dg][r] * linv[r]);
    }
}

// ---------------- RMSNorm rows of 1024 fp32 ----------------
__global__ __launch_bounds__(256) void k_rmsnorm(const float* __restrict__ in,
                                                 const float* __restrict__ wt,
                                                 float* __restrict__ out) {
  int row = blockIdx.x, tid = threadIdx.x;
  float4 v = ((const float4*)(in + (size_t)row * D_))[tid];
  float ss = v.x * v.x + v.y * v.y + v.z * v.z + v.w * v.w;
  for (int o = 32; o >= 1; o >>= 1) ss += __shfl_xor(ss, o);
  __shared__ float red[4];
  if ((tid & 63) == 0) red[tid >> 6] = ss;
  __syncthreads();
  float tot = red[0] + red[1] + red[2] + red[3];
  float rinv = 1.f / sqrtf(tot * (1.f / 1024.f) + 1e-6f);
  float4 wv = ((const float4*)wt)[tid];
  float4 o;
  o.x = v.x * rinv * wv.x;
  o.y = v.y * rinv * wv.y;
  o.z = v.z * rinv * wv.z;
  o.w = v.w * rinv * wv.w;
  ((float4*)(out + (size_t)row * D_))[tid] = o;
}

extern "C" void kernel_launch(void* const* d_in, const int* in_sizes, int n_in,
                              void* d_out, int out_size, void* d_ws, size_t ws_size,
                              hipStream_t stream) {
  const float* x  = (const float*)d_in[0];
  const float* Wq = (const float*)d_in[1];
  const float* Wk = (const float*)d_in[2];
  const float* Wv = (const float*)d_in[3];
  const float* Wo = (const float*)d_in[4];
  const float* nw = (const float*)d_in[5];
  float* out = (float*)d_out;

  char* p = (char*)d_ws;
  unsigned short* xb    = (unsigned short*)p; p += (size_t)MTOT * D_ * 2;        // 8 MB
  float*          qkv   = (float*)p;          p += (size_t)MTOT * NQKV * 4;      // 24 MB
  unsigned short* wqkvt = (unsigned short*)p; p += (size_t)NQKV * D_ * 2;        // 3 MB
  unsigned short* wot   = (unsigned short*)p; p += (size_t)D_ * D_ * 2;          // 2 MB
  unsigned short* qb    = (unsigned short*)p; p += (size_t)B_ * H_ * S_ * HD_ * 2;   // 8 MB
  unsigned short* kb    = (unsigned short*)p; p += (size_t)B_ * HKV_ * S_ * HD_ * 2; // 2 MB
  unsigned short* vtb   = (unsigned short*)p; p += (size_t)B_ * HKV_ * HD_ * S_ * 2; // 2 MB
  unsigned short* attnb = (unsigned short*)p; p += (size_t)MTOT * D_ * 2;        // 8 MB
  float*          proj  = (float*)p;          p += (size_t)MTOT * D_ * 4;        // 16 MB
  float*          cost  = (float*)p;          p += (size_t)S_ * 32 * 4;
  float*          sint  = (float*)p;          p += (size_t)S_ * 32 * 4;

  k_f32_to_bf16<<<1024, 256, 0, stream>>>(x, xb, MTOT * D_ / 4);
  k_rope_tables<<<256, 256, 0, stream>>>(cost, sint);
  k_transpose_w<<<dim3(16, 16), 256, 0, stream>>>(Wq, 1024, wqkvt, 1024);
  k_transpose_w<<<dim3(4, 16), 256, 0, stream>>>(Wk, 256, wqkvt + (size_t)1024 * 1024, 1024);
  k_transpose_w<<<dim3(4, 16), 256, 0, stream>>>(Wv, 256, wqkvt + (size_t)1280 * 1024, 1024);
  k_transpose_w<<<dim3(16, 16), 256, 0, stream>>>(Wo, 1024, wot, 1024);

  k_gemm_bt<<<dim3(NQKV / 128, MTOT / 128), 256, 0, stream>>>(xb, wqkvt, qkv, MTOT, NQKV, D_);
  k_rope_qk<<<MTOT, 256, 0, stream>>>(qkv, cost, sint, qb, kb);
  k_v_transpose<<<dim3(S_ / 64, B_ * HKV_), 256, 0, stream>>>(qkv, vtb);
  k_attn<<<dim3(S_ / 64, B_ * H_), 256, 0, stream>>>(qb, kb, vtb, attnb);
  k_gemm_bt<<<dim3(D_ / 128, MTOT / 128), 256, 0, stream>>>(attnb, wot, proj, MTOT, D_, D_);
  k_rmsnorm<<<MTOT, 256, 0, stream>>>(proj, nw, out);
}

// Round 2
// 163.662 us; speedup vs baseline: 1.1603x; 1.1603x over previous
//
#include <hip/hip_runtime.h>
#include <hip/hip_bf16.h>
#include <stdint.h>
#include <math.h>

typedef __bf16 bf16x8 __attribute__((ext_vector_type(8)));
typedef float f32x4 __attribute__((ext_vector_type(4)));
typedef float f32x16 __attribute__((ext_vector_type(16)));

#define B_    2
#define S_    2048
#define D_    1024
#define H_    16
#define HKV_  4
#define HD_   64
#define MTOT  4096      // B*S
#define NQKV  1536      // H*HD + 2*HKV*HD

#define ZERO16 {0.f,0.f,0.f,0.f,0.f,0.f,0.f,0.f,0.f,0.f,0.f,0.f,0.f,0.f,0.f,0.f}

__device__ __forceinline__ unsigned short f2bf(float f) {
  union { float f; unsigned u; } v; v.f = f;
  unsigned r = (v.u + 0x7FFFu + ((v.u >> 16) & 1u)) >> 16;
  return (unsigned short)r;
}

__device__ __forceinline__ unsigned cvt_pk_bf16(float lo, float hi) {
  unsigned r;
  asm("v_cvt_pk_bf16_f32 %0, %1, %2" : "=v"(r) : "v"(lo), "v"(hi));
  return r;
}

__device__ __forceinline__ void gl_lds16(const void* g, void* l) {
  __builtin_amdgcn_global_load_lds((const __attribute__((address_space(1))) void*)g,
                                   (__attribute__((address_space(3))) void*)l, 16, 0, 0);
}

// ---------------- fp32 -> bf16 elementwise ----------------
__global__ __launch_bounds__(256) void k_f32_to_bf16(const float* __restrict__ in,
                                                     unsigned short* __restrict__ out, int n4) {
  int i = blockIdx.x * blockDim.x + threadIdx.x;
  int stride = gridDim.x * blockDim.x;
  for (; i < n4; i += stride) {
    float4 v = ((const float4*)in)[i];
    ushort4 o;
    o.x = f2bf(v.x); o.y = f2bf(v.y); o.z = f2bf(v.z); o.w = f2bf(v.w);
    ((ushort4*)out)[i] = o;
  }
}

// ---------------- RoPE cos/sin tables [S][32] ----------------
__global__ __launch_bounds__(256) void k_rope_tables(float* __restrict__ cost, float* __restrict__ sint) {
  int idx = blockIdx.x * blockDim.x + threadIdx.x;   // 0..65535
  int s = idx >> 5, i = idx & 31;
  double inv = exp(-(double)i / 32.0 * log(10000.0));
  double ang = (double)s * inv;
  cost[idx] = (float)cos(ang);
  sint[idx] = (float)sin(ang);
}

// ---------------- transpose fp32 [R][C] -> bf16 [C][R] (64x64 tiles) ----------------
__global__ __launch_bounds__(256) void k_transpose_w(const float* __restrict__ src, int ldsrc,
                                                     unsigned short* __restrict__ dst, int lddst) {
  int cb = blockIdx.x * 64, rb = blockIdx.y * 64;
  __shared__ unsigned short T[64][72];
  int tid = threadIdx.x;
  for (int rep = 0; rep < 4; ++rep) {
    int idx = rep * 256 + tid;          // 0..1023
    int r = idx >> 4, seg = idx & 15;
    float4 v = *(const float4*)&src[(size_t)(rb + r) * ldsrc + cb + seg * 4];
    T[seg*4+0][r] = f2bf(v.x);
    T[seg*4+1][r] = f2bf(v.y);
    T[seg*4+2][r] = f2bf(v.z);
    T[seg*4+3][r] = f2bf(v.w);
  }
  __syncthreads();
  for (int rep = 0; rep < 2; ++rep) {
    int idx = rep * 256 + tid;          // 0..511
    int c = idx >> 3, seg = idx & 7;
    *(uint4*)&dst[(size_t)(cb + c) * lddst + rb + seg * 8] = *(const uint4*)&T[c][seg * 8];
  }
}

// ---------------- bf16 GEMM: C[M][N] = A[M][K] * Bt[N][K]^T  (m97-style 128x128) ----------------
__global__ __launch_bounds__(256) void k_gemm_bt(const unsigned short* __restrict__ A,
                                                 const unsigned short* __restrict__ Bt,
                                                 float* __restrict__ C, int M, int N, int K) {
  int nb = blockIdx.x, mb = blockIdx.y;
  __shared__ unsigned short As[128 * 32];
  __shared__ unsigned short Bs[128 * 32];
  int tid = threadIdx.x, lane = tid & 63, w = tid >> 6;
  int wr = w >> 1, wc = w & 1;
  f32x4 acc[4][4];
  for (int m = 0; m < 4; ++m) for (int n = 0; n < 4; ++n) acc[m][n] = (f32x4){0.f, 0.f, 0.f, 0.f};

  const int r16 = lane >> 2;          // row within 16-row segment
  const int c8  = (lane & 3) * 8;     // col (elements)

  auto stage = [&](int kt) {
    for (int j = 0; j < 2; ++j) {
      int rbase = (w * 2 + j) * 16;
      gl_lds16(&A [(size_t)(mb * 128 + rbase + r16) * K + kt * 32 + c8], &As[rbase * 32]);
      gl_lds16(&Bt[(size_t)(nb * 128 + rbase + r16) * K + kt * 32 + c8], &Bs[rbase * 32]);
    }
  };
  stage(0);
  int NT = K / 32;
  for (int kt = 0; kt < NT; ++kt) {
    __syncthreads();                  // staging complete (compiler drains vmcnt)
    bf16x8 af[4], bfr[4];
    int lr = lane & 15, lg8 = (lane >> 4) * 8;
    for (int m = 0; m < 4; ++m) af[m]  = *(const bf16x8*)&As[(wr * 64 + m * 16 + lr) * 32 + lg8];
    for (int n = 0; n < 4; ++n) bfr[n] = *(const bf16x8*)&Bs[(wc * 64 + n * 16 + lr) * 32 + lg8];
    for (int m = 0; m < 4; ++m)
      for (int n = 0; n < 4; ++n)
        acc[m][n] = __builtin_amdgcn_mfma_f32_16x16x32_bf16(af[m], bfr[n], acc[m][n], 0, 0, 0);
    __syncthreads();                  // all frag reads done before restage
    if (kt + 1 < NT) stage(kt + 1);
  }
  int lr = lane & 15, lq = (lane >> 4) * 4;
  for (int m = 0; m < 4; ++m)
    for (int n = 0; n < 4; ++n)
      for (int r = 0; r < 4; ++r)
        C[(size_t)(mb * 128 + wr * 64 + m * 16 + lq + r) * N + nb * 128 + wc * 64 + n * 16 + lr] = acc[m][n][r];
}

// ---------------- RoPE apply + layout: qkv fp32 -> Qb[B,H,S,64] (x0.125), Kb[B,HKV,S,64] bf16 ----------------
__global__ __launch_bounds__(256) void k_rope_qk(const float* __restrict__ qkv,
                                                 const float* __restrict__ cost,
                                                 const float* __restrict__ sint,
                                                 unsigned short* __restrict__ Qb,
                                                 unsigned short* __restrict__ Kb) {
  int blk = blockIdx.x;               // b*S + s
  int b = blk >> 11, s = blk & 2047;
  int tid = threadIdx.x;
  const float* row = qkv + (size_t)blk * NQKV;
  for (int rep = 0; rep < 4; ++rep) {
    int e = rep * 256 + tid;          // 0..1023
    int h = e >> 6, d = e & 63, d2 = d & 31;
    float c = cost[s * 32 + d2], sn = sint[s * 32 + d2];
    float x = row[e], xp = row[e ^ 32];
    float rot = (d < 32) ? -xp : xp;
    float o = (x * c + rot * sn) * 0.125f;   // fold 1/sqrt(64): exact in bf16
    Qb[(((size_t)(b * H_ + h)) * S_ + s) * HD_ + d] = f2bf(o);
  }
  {
    int e = tid;                      // 0..255
    int hk = e >> 6, d = e & 63, d2 = d & 31;
    float c = cost[s * 32 + d2], sn = sint[s * 32 + d2];
    float x = row[1024 + e], xp = row[1024 + (e ^ 32)];
    float rot = (d < 32) ? -xp : xp;
    float o = x * c + rot * sn;
    Kb[(((size_t)(b * HKV_ + hk)) * S_ + s) * HD_ + d] = f2bf(o);
  }
}

// ---------------- V transpose: qkv fp32 v-part -> Vt[B,HKV,64,S] bf16 ----------------
__global__ __launch_bounds__(256) void k_v_transpose(const float* __restrict__ qkv,
                                                     unsigned short* __restrict__ Vt) {
  int sb = blockIdx.x * 64;
  int b = blockIdx.y >> 2, hk = blockIdx.y & 3;
  __shared__ unsigned short T[64][72];
  int tid = threadIdx.x;
  for (int rep = 0; rep < 4; ++rep) {
    int idx = rep * 256 + tid;        // 0..1023
    int i = idx >> 4, seg = idx & 15;
    float4 v = *(const float4*)&qkv[((size_t)(b * S_ + sb + i)) * NQKV + 1280 + hk * 64 + seg * 4];
    T[seg*4+0][i] = f2bf(v.x);
    T[seg*4+1][i] = f2bf(v.y);
    T[seg*4+2][i] = f2bf(v.z);
    T[seg*4+3][i] = f2bf(v.w);
  }
  __syncthreads();
  for (int rep = 0; rep < 2; ++rep) {
    int idx = rep * 256 + tid;        // 0..511
    int d = idx >> 3, seg = idx & 7;
    *(uint4*)&Vt[(((size_t)(b * HKV_ + hk)) * HD_ + d) * S_ + sb + seg * 8] = *(const uint4*)&T[d][seg * 8];
  }
}

// ---------------- flash attention v2: 4 waves x 32 q-rows, 32x32x16 MFMA, KVBLK=64 ----------------
// Swapped QK^T (S^T = K*Q^T, lane col = q) and swapped PV (O^T = V^T*P^T, lane col = q):
// softmax state is lane-scalar. P redistribution in-register via cvt_pk + permlane32_swap (T12).
// K/Vt tiles in LDS, XOR-swizzled (chunk ^= row&7) with pre-swizzled global_load_lds source (rule 21).
__global__ __launch_bounds__(256, 2) void k_attn(const unsigned short* __restrict__ Q,
                                                 const unsigned short* __restrict__ K,
                                                 const unsigned short* __restrict__ Vt,
                                                 unsigned short* __restrict__ O) {
  int qt = blockIdx.x;                // 0..15 (q tile of 128)
  int bh = blockIdx.y;                // 0..31
  int b = bh >> 4, h = bh & 15, hk = h >> 2;
  const unsigned short* Qp = Q + (((size_t)(b * H_ + h)) * S_ + qt * 128) * HD_;
  const unsigned short* Kp = K + ((size_t)(b * HKV_ + hk)) * S_ * HD_;     // [S][64]
  const unsigned short* Vp = Vt + ((size_t)(b * HKV_ + hk)) * HD_ * S_;    // [64][S]

  __shared__ unsigned short Ks[2][64 * 64];   // [key][d], chunk-swizzled
  __shared__ unsigned short Vs[2][64 * 64];   // [d][key], chunk-swizzled

  const int tid = threadIdx.x, lane = tid & 63, w = tid >> 6;
  const int col = lane & 31;          // this lane's q (and A/B row/col index)
  const int hi  = lane >> 5;          // k-half selector
  const int sw  = lane & 7;           // row&7 for all our swizzled reads (rows = col mod 32-blocks)

  // Q fragments in registers: B[k=d][col=q], lane holds Q[q=col][dc*16 + hi*8 .. +7]
  bf16x8 qf[4];
  {
    const unsigned short* qrow = Qp + (size_t)(w * 32 + col) * HD_;
    #pragma unroll
    for (int dc = 0; dc < 4; ++dc)
      qf[dc] = *(const bf16x8*)&qrow[dc * 16 + hi * 8];
  }

  f32x16 oacc0 = ZERO16, oacc1 = ZERO16;
  float m_run = -3.0e38f, l_run = 0.f;

  // stage one K/V tile (16 rows per wave, 8 rows per gl_lds issue), pre-swizzled source
  auto stage = [&](int buf, int kt) {
    int rl = lane >> 3;               // row within 8-row group
    int cs = lane & 7;                // LDS chunk slot this lane fills
    #pragma unroll
    for (int j = 0; j < 2; ++j) {
      int row = w * 16 + j * 8 + rl;  // 0..63
      int csrc = ((cs ^ (row & 7)) * 8);   // source chunk (elements)
      gl_lds16(&Kp[(size_t)(kt * 64 + row) * HD_ + csrc], &Ks[buf][(w * 16 + j * 8) * 64]);
      gl_lds16(&Vp[(size_t)row * S_ + kt * 64 + csrc],    &Vs[buf][(w * 16 + j * 8) * 64]);
    }
  };

  stage(0, 0);
  int cur = 0;
  const float LOG2E = 1.44269504f;

  for (int kt = 0; kt < S_ / 64; ++kt) {
    __syncthreads();                  // drains vmcnt: buf[cur] staged; prev-tile reads done
    if (kt + 1 < S_ / 64) stage(cur ^ 1, kt + 1);

    // ---- QK^T: S^T[key][q], two 32-key blocks ----
    f32x16 st0 = ZERO16, st1 = ZERO16;
    {
      const unsigned short* kb = &Ks[cur][0];
      int r0 = col * 64, r1 = (32 + col) * 64;
      #pragma unroll
      for (int dc = 0; dc < 4; ++dc) {
        int ch = ((dc * 2 + hi) ^ sw) * 8;
        bf16x8 k0 = *(const bf16x8*)&kb[r0 + ch];
        bf16x8 k1 = *(const bf16x8*)&kb[r1 + ch];
        st0 = __builtin_amdgcn_mfma_f32_32x32x16_bf16(k0, qf[dc], st0, 0, 0, 0);
        st1 = __builtin_amdgcn_mfma_f32_32x32x16_bf16(k1, qf[dc], st1, 0, 0, 0);
      }
    }

    // ---- online softmax (per-lane scalar state; keys split across lane ^ 32) ----
    float tmax = -3.0e38f;
    #pragma unroll
    for (int i = 0; i < 16; ++i) {
      tmax = fmaxf(tmax, st0[i]);
      tmax = fmaxf(tmax, st1[i]);
    }
    tmax = fmaxf(tmax, __shfl_xor(tmax, 32));
    float m_new = fmaxf(m_run, tmax);
    float fac = exp2f((m_run - m_new) * LOG2E);
    float mb = m_new * LOG2E;
    float psum = 0.f;
    #pragma unroll
    for (int i = 0; i < 16; ++i) {
      float p0 = exp2f(fmaf(st0[i], LOG2E, -mb));
      float p1 = exp2f(fmaf(st1[i], LOG2E, -mb));
      st0[i] = p0; st1[i] = p1;
      psum += p0 + p1;
    }
    psum += __shfl_xor(psum, 32);
    l_run = l_run * fac + psum;
    m_run = m_new;

    // ---- P -> bf16 fragments via cvt_pk + permlane32_swap (T12) ----
    bf16x8 pf[4];
    #pragma unroll
    for (int kb2 = 0; kb2 < 2; ++kb2) {
      const f32x16& s = kb2 ? st1 : st0;
      #pragma unroll
      for (int kcl = 0; kcl < 2; ++kcl) {
        int base = kcl * 8;
        unsigned u0 = cvt_pk_bf16(s[base + 0], s[base + 1]);
        unsigned u1 = cvt_pk_bf16(s[base + 2], s[base + 3]);
        unsigned u2 = cvt_pk_bf16(s[base + 4], s[base + 5]);
        unsigned u3 = cvt_pk_bf16(s[base + 6], s[base + 7]);
        asm("v_permlane32_swap_b32 %0, %1" : "+v"(u0), "+v"(u2));  // -> word0, word2
        asm("v_permlane32_swap_b32 %0, %1" : "+v"(u1), "+v"(u3));  // -> word1, word3
        union { unsigned u[4]; bf16x8 v; } pk;
        pk.u[0] = u0; pk.u[1] = u1; pk.u[2] = u2; pk.u[3] = u3;
        pf[kb2 * 2 + kcl] = pk.v;
      }
    }

    // ---- rescale O^T and PV: O^T[d][q] += V^T[d][key] * P^T[key][q] ----
    #pragma unroll
    for (int i = 0; i < 16; ++i) { oacc0[i] *= fac; oacc1[i] *= fac; }
    {
      const unsigned short* vb = &Vs[cur][0];
      int r0 = col * 64, r1 = (32 + col) * 64;
      #pragma unroll
      for (int kc = 0; kc < 4; ++kc) {
        int ch = ((kc * 2 + hi) ^ sw) * 8;
        bf16x8 v0 = *(const bf16x8*)&vb[r0 + ch];
        bf16x8 v1 = *(const bf16x8*)&vb[r1 + ch];
        oacc0 = __builtin_amdgcn_mfma_f32_32x32x16_bf16(v0, pf[kc], oacc0, 0, 0, 0);
        oacc1 = __builtin_amdgcn_mfma_f32_32x32x16_bf16(v1, pf[kc], oacc1, 0, 0, 0);
      }
    }
    cur ^= 1;
  }

  // ---- epilogue: O[q][d] = O^T[d][q] / l ----
  float linv = 1.f / l_run;
  int qrow = qt * 128 + w * 32 + col;
  unsigned short* obase = O + ((size_t)(b * S_) + qrow) * D_ + h * 64;
  #pragma unroll
  for (int r = 0; r < 16; ++r) {
    int dp = (r & 3) + 8 * (r >> 2) + 4 * hi;
    obase[dp]      = f2bf(oacc0[r] * linv);
    obase[32 + dp] = f2bf(oacc1[r] * linv);
  }
}

// ---------------- RMSNorm rows of 1024 fp32 ----------------
__global__ __launch_bounds__(256) void k_rmsnorm(const float* __restrict__ in,
                                                 const float* __restrict__ wt,
                                                 float* __restrict__ out) {
  int row = blockIdx.x, tid = threadIdx.x;
  float4 v = ((const float4*)(in + (size_t)row * D_))[tid];
  float ss = v.x * v.x + v.y * v.y + v.z * v.z + v.w * v.w;
  for (int o = 32; o >= 1; o >>= 1) ss += __shfl_xor(ss, o);
  __shared__ float red[4];
  if ((tid & 63) == 0) red[tid >> 6] = ss;
  __syncthreads();
  float tot = red[0] + red[1] + red[2] + red[3];
  float rinv = 1.f / sqrtf(tot * (1.f / 1024.f) + 1e-6f);
  float4 wv = ((const float4*)wt)[tid];
  float4 o;
  o.x = v.x * rinv * wv.x;
  o.y = v.y * rinv * wv.y;
  o.z = v.z * rinv * wv.z;
  o.w = v.w * rinv * wv.w;
  ((float4*)(out + (size_t)row * D_))[tid] = o;
}

extern "C" void kernel_launch(void* const* d_in, const int* in_sizes, int n_in,
                              void* d_out, int out_size, void* d_ws, size_t ws_size,
                              hipStream_t stream) {
  const float* x  = (const float*)d_in[0];
  const float* Wq = (const float*)d_in[1];
  const float* Wk = (const float*)d_in[2];
  const float* Wv = (const float*)d_in[3];
  const float* Wo = (const float*)d_in[4];
  const float* nw = (const float*)d_in[5];
  float* out = (float*)d_out;

  char* p = (char*)d_ws;
  unsigned short* xb    = (unsigned short*)p; p += (size_t)MTOT * D_ * 2;        // 8 MB
  float*          qkv   = (float*)p;          p += (size_t)MTOT * NQKV * 4;      // 24 MB
  unsigned short* wqkvt = (unsigned short*)p; p += (size_t)NQKV * D_ * 2;        // 3 MB
  unsigned short* wot   = (unsigned short*)p; p += (size_t)D_ * D_ * 2;          // 2 MB
  unsigned short* qb    = (unsigned short*)p; p += (size_t)B_ * H_ * S_ * HD_ * 2;   // 8 MB
  unsigned short* kb    = (unsigned short*)p; p += (size_t)B_ * HKV_ * S_ * HD_ * 2; // 2 MB
  unsigned short* vtb   = (unsigned short*)p; p += (size_t)B_ * HKV_ * HD_ * S_ * 2; // 2 MB
  unsigned short* attnb = (unsigned short*)p; p += (size_t)MTOT * D_ * 2;        // 8 MB
  float*          proj  = (float*)p;          p += (size_t)MTOT * D_ * 4;        // 16 MB
  float*          cost  = (float*)p;          p += (size_t)S_ * 32 * 4;
  float*          sint  = (float*)p;          p += (size_t)S_ * 32 * 4;

  k_f32_to_bf16<<<1024, 256, 0, stream>>>(x, xb, MTOT * D_ / 4);
  k_rope_tables<<<256, 256, 0, stream>>>(cost, sint);
  k_transpose_w<<<dim3(16, 16), 256, 0, stream>>>(Wq, 1024, wqkvt, 1024);
  k_transpose_w<<<dim3(4, 16), 256, 0, stream>>>(Wk, 256, wqkvt + (size_t)1024 * 1024, 1024);
  k_transpose_w<<<dim3(4, 16), 256, 0, stream>>>(Wv, 256, wqkvt + (size_t)1280 * 1024, 1024);
  k_transpose_w<<<dim3(16, 16), 256, 0, stream>>>(Wo, 1024, wot, 1024);

  k_gemm_bt<<<dim3(NQKV / 128, MTOT / 128), 256, 0, stream>>>(xb, wqkvt, qkv, MTOT, NQKV, D_);
  k_rope_qk<<<MTOT, 256, 0, stream>>>(qkv, cost, sint, qb, kb);
  k_v_transpose<<<dim3(S_ / 64, B_ * HKV_), 256, 0, stream>>>(qkv, vtb);
  k_attn<<<dim3(S_ / 128, B_ * H_), 256, 0, stream>>>(qb, kb, vtb, attnb);
  k_gemm_bt<<<dim3(D_ / 128, MTOT / 128), 256, 0, stream>>>(attnb, wot, proj, MTOT, D_, D_);
  k_rmsnorm<<<MTOT, 256, 0, stream>>>(proj, nw, out);
}